// Round 4
// baseline (442.151 us; speedup 1.0000x reference)
//
#include <hip/hip_runtime.h>

typedef _Float16 f16;
typedef _Float16 f16x8 __attribute__((ext_vector_type(8)));
typedef _Float16 f16x4 __attribute__((ext_vector_type(4)));
typedef float f32x4 __attribute__((ext_vector_type(4)));

#define NH 4
#define HD 256
#define BB 4
#define SS 2048
#define HID 1152
#define QKV_N 1536
#define ODIM (NH * HD)

#define OPART_OFF 33554432L
#define ML_OFF 81395712L

// ---------------------------------------------------------------------------
// Transpose + fp32->fp16 convert:  dst[c][r] = (f16) src[r][c]
// ---------------------------------------------------------------------------
__global__ __launch_bounds__(256) void transpose_cvt(
    const float* __restrict__ src, long src_ld, long src_bs,
    f16* __restrict__ dst, long dst_ld, long dst_bs) {
  __shared__ float tile[32][33];
  src += (long)blockIdx.z * src_bs;
  dst += (long)blockIdx.z * dst_bs;
  int r0 = blockIdx.y * 32, c0 = blockIdx.x * 32;
  int tc = threadIdx.x & 31, tr = threadIdx.x >> 5;
#pragma unroll
  for (int i = 0; i < 4; ++i)
    tile[tr + i * 8][tc] = src[(long)(r0 + tr + i * 8) * src_ld + c0 + tc];
  __syncthreads();
#pragma unroll
  for (int i = 0; i < 4; ++i)
    dst[(long)(c0 + tr + i * 8) * dst_ld + r0 + tc] = (f16)tile[tc][tr + i * 8];
}

// ---------------------------------------------------------------------------
// GEMM: C[M][N] fp32 = A[M][K] fp32  x  Bt[N][K] fp16
// ---------------------------------------------------------------------------
__global__ __launch_bounds__(256, 2) void gemm_a32_b16(
    const float* __restrict__ A, const f16* __restrict__ Bt,
    float* __restrict__ C, int K, int N) {
  __shared__ f16 As[128][40];
  __shared__ f16 Bs[128][40];
  int tid = threadIdx.x;
  int wave = tid >> 6, lane = tid & 63;
  int l16 = lane & 15, lhi = lane >> 4;
  int wm = (wave >> 1) * 64, wn = (wave & 1) * 64;
  long bm = (long)blockIdx.x * 128, bn = (long)blockIdx.y * 128;
  f32x4 acc[4][4] = {};
  int a_kq = (tid & 7) * 4, a_r = tid >> 3;
  int b_ko = (tid & 3) * 8, b_r = tid >> 2;

  for (int k0 = 0; k0 < K; k0 += 32) {
#pragma unroll
    for (int i = 0; i < 4; ++i) {
      int r = a_r + 32 * i;
      float4 v = *(const float4*)&A[(bm + r) * K + k0 + a_kq];
      f16x4 h = {(f16)v.x, (f16)v.y, (f16)v.z, (f16)v.w};
      *(f16x4*)&As[r][a_kq] = h;
    }
#pragma unroll
    for (int i = 0; i < 2; ++i) {
      int r = b_r + 64 * i;
      *(uint4*)&Bs[r][b_ko] = *(const uint4*)&Bt[(bn + r) * K + k0 + b_ko];
    }
    __syncthreads();
    f16x8 af[4], bf[4];
#pragma unroll
    for (int i = 0; i < 4; ++i)
      af[i] = *(const f16x8*)&As[wm + i * 16 + l16][lhi * 8];
#pragma unroll
    for (int j = 0; j < 4; ++j)
      bf[j] = *(const f16x8*)&Bs[wn + j * 16 + l16][lhi * 8];
#pragma unroll
    for (int i = 0; i < 4; ++i)
#pragma unroll
      for (int j = 0; j < 4; ++j)
        acc[i][j] = __builtin_amdgcn_mfma_f32_16x16x32_f16(af[i], bf[j], acc[i][j], 0, 0, 0);
    __syncthreads();
  }
#pragma unroll
  for (int i = 0; i < 4; ++i) {
    long row = bm + wm + i * 16 + lhi * 4;
#pragma unroll
    for (int r = 0; r < 4; ++r) {
      float* crow = C + (row + r) * N + bn + wn + l16;
#pragma unroll
      for (int j = 0; j < 4; ++j) crow[j * 16] = acc[i][j][r];
    }
  }
}

// ---------------------------------------------------------------------------
// RMSNorm + RoPE + scale, qkv fp32 -> Q/K fp16
// ---------------------------------------------------------------------------
__device__ __forceinline__ void norm_rope_store(
    const float* __restrict__ x, const float* __restrict__ w,
    const float* __restrict__ fc, const float* __restrict__ fs,
    f16* __restrict__ dst, float scale, int lane) {
  float x0 = x[lane], x1 = x[lane + 64], x2 = x[lane + 128], x3 = x[lane + 192];
  float ss = x0 * x0 + x1 * x1 + x2 * x2 + x3 * x3;
#pragma unroll
  for (int m = 1; m < 64; m <<= 1) ss += __shfl_xor(ss, m, 64);
  float inv = rsqrtf(ss * (1.0f / 256.0f) + 1e-6f);
  x0 *= inv * (1.0f + w[lane]);
  x1 *= inv * (1.0f + w[lane + 64]);
  x2 *= inv * (1.0f + w[lane + 128]);
  x3 *= inv * (1.0f + w[lane + 192]);
  float c0 = fc[lane], s0 = fs[lane], c1 = fc[lane + 64], s1 = fs[lane + 64];
  dst[lane]       = (f16)((x0 * c0 - x2 * s0) * scale);
  dst[lane + 64]  = (f16)((x1 * c1 - x3 * s1) * scale);
  dst[lane + 128] = (f16)((x0 * s0 + x2 * c0) * scale);
  dst[lane + 192] = (f16)((x1 * s1 + x3 * c1) * scale);
}

__global__ __launch_bounds__(256) void qkv_post(
    const float* __restrict__ qkv, const float* __restrict__ qnw,
    const float* __restrict__ knw, const float* __restrict__ fcos,
    const float* __restrict__ fsin, f16* __restrict__ Q, f16* __restrict__ Kb) {
  long row = blockIdx.x;
  int b = (int)(row >> 11), s = (int)(row & 2047);
  int wave = threadIdx.x >> 6, lane = threadIdx.x & 63;
  const float* base = qkv + row * QKV_N;
  const float* fc = fcos + (long)s * 128;
  const float* fs = fsin + (long)s * 128;
  norm_rope_store(base + wave * HD, qnw, fc, fs,
                  Q + ((long)(b * NH + wave) * SS + s) * HD, 0.0625f, lane);
  if (wave == 0)
    norm_rope_store(base + NH * HD, knw, fc, fs, Kb + row * HD, 1.0f, lane);
}

// ---------------------------------------------------------------------------
// Flash attention, causal, GQA, kv-split for load balance.
// NO K/V LDS staging: fragments load straight from global (L1/L2-resident),
// no __syncthreads in the kv loop, waves fully independent.
// grid: (48, NH, B), block 256 (4 waves x 16 q-rows), KVBLK=32.
// ---------------------------------------------------------------------------
__global__ __launch_bounds__(256, 3) void attn_fwd(
    const f16* __restrict__ Q, const f16* __restrict__ Kb,
    const f16* __restrict__ Vt, float* __restrict__ O,
    f16* __restrict__ Opart, float2* __restrict__ ml) {
  __shared__ f16 Plds[4][16][40];  // per-wave P tile [q][kv]
  int it = blockIdx.x, h = blockIdx.y, b = blockIdx.z;
  int qb, t0, t1, pidx = 0;
  bool split;
  if (it < 16) {
    qb = it; t0 = 0; t1 = 2 * qb + 2; split = false;
  } else {
    int j = it - 16;
    qb = 16 + (j >> 1);
    int s = j & 1, half = qb + 1;
    t0 = s * half; t1 = t0 + half; split = true;
    pidx = (((b * NH + h) << 4) + (qb - 16)) * 2 + s;
  }
  int tid = threadIdx.x, wave = tid >> 6, lane = tid & 63;
  int l16 = lane & 15, lhi = lane >> 4;
  int q0 = qb * 64 + wave * 16;

  const f16* Kg = Kb + (long)b * SS * HD;
  const f16* Vg = Vt + (long)b * HD * SS;

  // Q fragments (B-operand: q on lane&15, d-slice on lhi)
  f16x8 qf[8];
  const f16* Qbase = Q + ((long)(b * NH + h) * SS + q0 + l16) * HD + lhi * 8;
#pragma unroll
  for (int kb = 0; kb < 8; ++kb) qf[kb] = *(const f16x8*)(Qbase + kb * 32);

  f32x4 o[16] = {};
  float m_i = -1e30f, l_i = 0.f;

  for (int t = t0; t < t1; ++t) {
    int kv0 = t * 32;
    // QK^T swapped: mfma(K, Q) -> D[kv_local][q=l16]; K frags direct global.
    // Each frag load: 16 rows x 64B contiguous -> full 64B lines, L1/L2 hit.
    const f16* Kt = Kg + (long)(kv0 + l16) * HD + lhi * 8;
    f32x4 sc[2] = {};
#pragma unroll
    for (int kb = 0; kb < 8; ++kb) {
#pragma unroll
      for (int cf = 0; cf < 2; ++cf) {
        f16x8 kf = *(const f16x8*)(Kt + (long)cf * 16 * HD + kb * 32);
        sc[cf] = __builtin_amdgcn_mfma_f32_16x16x32_f16(kf, qf[kb], sc[cf], 0, 0, 0);
      }
    }

    // online softmax: lane owns q-row q0+l16, 8 scores in-register
    float p[8];
    float mx = -1e30f;
    int qrow = q0 + l16;
    if (t >= 2 * qb) {  // diagonal tiles need the causal mask
#pragma unroll
      for (int cf = 0; cf < 2; ++cf)
#pragma unroll
        for (int r = 0; r < 4; ++r) {
          int kv = kv0 + cf * 16 + lhi * 4 + r;
          float s = (kv <= qrow) ? sc[cf][r] : -1e30f;
          p[cf * 4 + r] = s;
          mx = fmaxf(mx, s);
        }
    } else {
#pragma unroll
      for (int i = 0; i < 8; ++i) {
        float s = sc[i >> 2][i & 3];
        p[i] = s;
        mx = fmaxf(mx, s);
      }
    }
    mx = fmaxf(mx, __shfl_xor(mx, 16));
    mx = fmaxf(mx, __shfl_xor(mx, 32));
    float mn = fmaxf(m_i, mx);
    float scl = __expf(m_i - mn);
    float rs = 0.f;
#pragma unroll
    for (int i = 0; i < 8; ++i) {
      p[i] = __expf(p[i] - mn);
      rs += p[i];
    }
    rs += __shfl_xor(rs, 16);
    rs += __shfl_xor(rs, 32);
    l_i = l_i * scl + rs;
    m_i = mn;

    // P -> f16 into per-wave LDS [q][kv]
#pragma unroll
    for (int cf = 0; cf < 2; ++cf) {
      f16x4 hp = {(f16)p[cf * 4], (f16)p[cf * 4 + 1], (f16)p[cf * 4 + 2],
                  (f16)p[cf * 4 + 3]};
      *(f16x4*)&Plds[wave][l16][cf * 16 + lhi * 4] = hp;
    }

    // rescale O by scl of the owning q-row
    float s0 = __shfl(scl, lhi * 4 + 0);
    float s1 = __shfl(scl, lhi * 4 + 1);
    float s2 = __shfl(scl, lhi * 4 + 2);
    float s3 = __shfl(scl, lhi * 4 + 3);
#pragma unroll
    for (int nf = 0; nf < 16; ++nf) {
      o[nf][0] *= s0;
      o[nf][1] *= s1;
      o[nf][2] *= s2;
      o[nf][3] *= s3;
    }

    // PV: o[q=lhi*4+r][d=nf*16+l16] += P x V; V frags direct global.
    // Each frag load: 16 fully-used 64B lines of Vt (rows d, 32 kv each).
    f16x8 pa = *(const f16x8*)&Plds[wave][l16][lhi * 8];
    const f16* Vr = Vg + (long)l16 * SS + kv0 + lhi * 8;
#pragma unroll
    for (int nf = 0; nf < 16; ++nf) {
      f16x8 vf = *(const f16x8*)(Vr + (long)nf * 16 * SS);
      o[nf] = __builtin_amdgcn_mfma_f32_16x16x32_f16(pa, vf, o[nf], 0, 0, 0);
    }
  }

  // epilogue
  float inv = 1.0f / l_i;  // lane's q-row = q0 + l16
  float i0 = __shfl(inv, lhi * 4 + 0);
  float i1 = __shfl(inv, lhi * 4 + 1);
  float i2 = __shfl(inv, lhi * 4 + 2);
  float i3 = __shfl(inv, lhi * 4 + 3);
  float ir[4] = {i0, i1, i2, i3};
  if (!split) {
#pragma unroll
    for (int r = 0; r < 4; ++r) {
      long srow = q0 + lhi * 4 + r;
      float* Orow = O + ((long)b * SS + srow) * ODIM + h * HD + l16;
#pragma unroll
      for (int nf = 0; nf < 16; ++nf) Orow[nf * 16] = o[nf][r] * ir[r];
    }
  } else {
#pragma unroll
    for (int r = 0; r < 4; ++r) {
      int rloc = wave * 16 + lhi * 4 + r;
      f16* Prow = Opart + ((long)pidx * 64 + rloc) * HD + l16;
#pragma unroll
      for (int nf = 0; nf < 16; ++nf) Prow[nf * 16] = (f16)(o[nf][r] * ir[r]);
    }
    if (lane < 16) {
      float2 v; v.x = m_i; v.y = l_i;
      ml[(long)pidx * 64 + wave * 16 + lane] = v;
    }
  }
}

// ---------------------------------------------------------------------------
// Combine the two kv-split halves for qb >= 16.
// ---------------------------------------------------------------------------
__global__ __launch_bounds__(256) void attn_combine(
    const f16* __restrict__ Opart, const float2* __restrict__ ml,
    float* __restrict__ O) {
  int qx = blockIdx.x, h = blockIdx.y, b = blockIdx.z;
  int qb = 16 + qx;
  int p0 = (((b * NH + h) << 4) + qx) * 2;
  int tid = threadIdx.x;
  int r = tid >> 2, d0 = (tid & 3) * 64;
  float2 a = ml[(long)p0 * 64 + r];
  float2 c = ml[(long)(p0 + 1) * 64 + r];
  float M = fmaxf(a.x, c.x);
  float w0 = a.y * __expf(a.x - M), w1 = c.y * __expf(c.x - M);
  float invL = 1.0f / (w0 + w1);
  w0 *= invL; w1 *= invL;
  const f16* o0 = Opart + ((long)p0 * 64 + r) * HD + d0;
  const f16* o1 = Opart + ((long)(p0 + 1) * 64 + r) * HD + d0;
  float* Orow = O + ((long)b * SS + qb * 64 + r) * ODIM + h * HD + d0;
#pragma unroll
  for (int i = 0; i < 8; ++i) {
    f16x8 x = *(const f16x8*)(o0 + i * 8);
    f16x8 y = *(const f16x8*)(o1 + i * 8);
#pragma unroll
    for (int j = 0; j < 8; ++j)
      Orow[i * 8 + j] = w0 * (float)x[j] + w1 * (float)y[j];
  }
}

// ---------------------------------------------------------------------------
extern "C" void kernel_launch(void* const* d_in, const int* in_sizes, int n_in,
                              void* d_out, int out_size, void* d_ws, size_t ws_size,
                              hipStream_t stream) {
  const float* hidden = (const float*)d_in[0];
  const float* fcos = (const float*)d_in[2];
  const float* fsin = (const float*)d_in[3];
  const float* wqkv = (const float*)d_in[4];
  const float* qnw = (const float*)d_in[5];
  const float* knw = (const float*)d_in[6];
  const float* wo = (const float*)d_in[7];
  float* out = (float*)d_out;

  char* ws = (char*)d_ws;
  float* qkv = (float*)(ws + 0);
  float* Obuf = (float*)(ws + 0);
  f16* Opart = (f16*)(ws + OPART_OFF);
  f16* Qb = (f16*)(ws + 50331648);
  f16* Kb = (f16*)(ws + 67108864);
  f16* Vt = (f16*)(ws + 71303168);
  f16* wqkvt = (f16*)(ws + 75497472);
  f16* wot = (f16*)(ws + 79036416);
  float2* ml = (float2*)(ws + ML_OFF);

  transpose_cvt<<<dim3(QKV_N / 32, HID / 32, 1), 256, 0, stream>>>(
      wqkv, QKV_N, 0, wqkvt, HID, 0);
  transpose_cvt<<<dim3(HID / 32, ODIM / 32, 1), 256, 0, stream>>>(
      wo, HID, 0, wot, ODIM, 0);

  gemm_a32_b16<<<dim3(BB * SS / 128, QKV_N / 128), 256, 0, stream>>>(
      hidden, wqkvt, qkv, HID, QKV_N);

  qkv_post<<<dim3(BB * SS), 256, 0, stream>>>(qkv, qnw, knw, fcos, fsin, Qb, Kb);

  transpose_cvt<<<dim3(HD / 32, SS / 32, BB), 256, 0, stream>>>(
      qkv + 1280, QKV_N, (long)SS * QKV_N, Vt, SS, (long)HD * SS);

  attn_fwd<<<dim3(48, NH, BB), 256, 0, stream>>>(Qb, Kb, Vt, Obuf, Opart, ml);

  attn_combine<<<dim3(16, NH, BB), 256, 0, stream>>>(Opart, ml, Obuf);

  gemm_a32_b16<<<dim3(BB * SS / 128, HID / 128), 256, 0, stream>>>(
      Obuf, wot, out, ODIM, HID);
}

// Round 5
// 236.985 us; speedup vs baseline: 1.8657x; 1.8657x over previous
//
#include <hip/hip_runtime.h>

typedef _Float16 f16;
typedef _Float16 f16x8 __attribute__((ext_vector_type(8)));
typedef _Float16 f16x4 __attribute__((ext_vector_type(4)));
typedef float f32x4 __attribute__((ext_vector_type(4)));

#define NH 4
#define HD 256
#define BB 4
#define SS 2048
#define HID 1152
#define QKV_N 1536
#define ODIM (NH * HD)

#define QKV16_OFF 0L
#define HID16_OFF 25165824L
#define OBUF_OFF 0L
#define OPART_OFF 33554432L
#define QB_OFF 50331648L
#define KB_OFF 67108864L
#define VT_OFF 71303168L
#define WQKVT_OFF 75497472L
#define WOT_OFF 79036416L
#define ML_OFF 81395712L

// async global->LDS, 16B per lane; LDS dest = wave-uniform base + lane*16
#define GLL16(gp, lp)                                                      \
  __builtin_amdgcn_global_load_lds(                                       \
      (const __attribute__((address_space(1))) char*)(gp),                \
      (__attribute__((address_space(3))) char*)(lp), 16, 0, 0)

// ---------------------------------------------------------------------------
// fp32 -> fp16 bulk convert (vectorized, grid-stride)
// ---------------------------------------------------------------------------
__global__ __launch_bounds__(256) void cvt_f32_to_f16(
    const float* __restrict__ s, f16* __restrict__ d, long n) {
  long i = ((long)blockIdx.x * 256 + threadIdx.x) * 8;
  long stride = (long)gridDim.x * 256 * 8;
  for (; i < n; i += stride) {
    float4 a = *(const float4*)(s + i);
    float4 b = *(const float4*)(s + i + 4);
    f16x8 h = {(f16)a.x, (f16)a.y, (f16)a.z, (f16)a.w,
               (f16)b.x, (f16)b.y, (f16)b.z, (f16)b.w};
    *(f16x8*)(d + i) = h;
  }
}

// ---------------------------------------------------------------------------
// Transpose + convert to fp16:  dst[c][r] = (f16) src[r][c]
// ---------------------------------------------------------------------------
template <typename ST>
__global__ __launch_bounds__(256) void transpose_cvt(
    const ST* __restrict__ src, long src_ld, long src_bs,
    f16* __restrict__ dst, long dst_ld, long dst_bs) {
  __shared__ float tile[32][33];
  src += (long)blockIdx.z * src_bs;
  dst += (long)blockIdx.z * dst_bs;
  int r0 = blockIdx.y * 32, c0 = blockIdx.x * 32;
  int tc = threadIdx.x & 31, tr = threadIdx.x >> 5;
#pragma unroll
  for (int i = 0; i < 4; ++i)
    tile[tr + i * 8][tc] = (float)src[(long)(r0 + tr + i * 8) * src_ld + c0 + tc];
  __syncthreads();
#pragma unroll
  for (int i = 0; i < 4; ++i)
    dst[(long)(c0 + tr + i * 8) * dst_ld + r0 + tc] = (f16)tile[tc][tr + i * 8];
}

// ---------------------------------------------------------------------------
// GEMM: C[M][N] = A[M][K] fp16 x Bt[N][K] fp16, C fp16 or fp32.
// m97 structure: 128x128 tile, BK=64, linear LDS, global_load_lds 16B,
// 2-barrier loop. Swapped MFMA operands -> row-contiguous C fragments.
// grid: (M/128, N/128), block 256.
// ---------------------------------------------------------------------------
template <typename CT>
__global__ __launch_bounds__(256, 3) void gemm_f16(
    const f16* __restrict__ A, const f16* __restrict__ Bt,
    CT* __restrict__ C, int K, int N) {
  __shared__ f16 As[128][64];
  __shared__ f16 Bs[128][64];
  int tid = threadIdx.x, wave = tid >> 6, lane = tid & 63;
  int l16 = lane & 15, lhi = lane >> 4;
  int wm = (wave >> 1) * 64, wn = (wave & 1) * 64;
  long bm = (long)blockIdx.x * 128, bn = (long)blockIdx.y * 128;
  f32x4 acc[4][4] = {};

  // staging: wave w stages rows w*32..w*32+31 of A and B (8 rows / instr)
  int srow = wave * 32 + (lane >> 3);
  int scol = (lane & 7) * 8;
  const f16* Ag = A + (bm + srow) * (long)K + scol;
  const f16* Bg = Bt + (bn + srow) * (long)K + scol;

  for (int k0 = 0; k0 < K; k0 += 64) {
#pragma unroll
    for (int i = 0; i < 4; ++i)
      GLL16(Ag + k0 + (long)i * 8 * K, &As[wave * 32 + i * 8][0]);
#pragma unroll
    for (int i = 0; i < 4; ++i)
      GLL16(Bg + k0 + (long)i * 8 * K, &Bs[wave * 32 + i * 8][0]);
    __syncthreads();  // drains vmcnt(0): staged tile visible
#pragma unroll
    for (int kb = 0; kb < 2; ++kb) {
      f16x8 af[4], bf[4];
#pragma unroll
      for (int i = 0; i < 4; ++i)
        af[i] = *(const f16x8*)&As[wm + i * 16 + l16][kb * 32 + lhi * 8];
#pragma unroll
      for (int j = 0; j < 4; ++j)
        bf[j] = *(const f16x8*)&Bs[wn + j * 16 + l16][kb * 32 + lhi * 8];
#pragma unroll
      for (int i = 0; i < 4; ++i)
#pragma unroll
        for (int j = 0; j < 4; ++j)
          acc[i][j] =
              __builtin_amdgcn_mfma_f32_16x16x32_f16(bf[j], af[i], acc[i][j], 0, 0, 0);
    }
    __syncthreads();  // protect LDS before next stage
  }

  // epilogue: m = bm+wm+i*16+l16 (lane-row), n = bn+wn+j*16+lhi*4 (+reg)
#pragma unroll
  for (int i = 0; i < 4; ++i) {
    long m = bm + wm + i * 16 + l16;
#pragma unroll
    for (int j = 0; j < 4; ++j) {
      long n = bn + wn + j * 16 + lhi * 4;
      if constexpr (sizeof(CT) == 2) {
        f16x4 h = {(f16)acc[i][j][0], (f16)acc[i][j][1], (f16)acc[i][j][2],
                   (f16)acc[i][j][3]};
        *(f16x4*)&C[m * N + n] = h;
      } else {
        *(f32x4*)&C[m * N + n] = acc[i][j];
      }
    }
  }
}

// ---------------------------------------------------------------------------
// RMSNorm + RoPE + scale, qkv fp16 -> Q/K fp16
// ---------------------------------------------------------------------------
__device__ __forceinline__ void norm_rope_store(
    const f16* __restrict__ x, const float* __restrict__ w,
    const float* __restrict__ fc, const float* __restrict__ fs,
    f16* __restrict__ dst, float scale, int lane) {
  float x0 = (float)x[lane], x1 = (float)x[lane + 64];
  float x2 = (float)x[lane + 128], x3 = (float)x[lane + 192];
  float ss = x0 * x0 + x1 * x1 + x2 * x2 + x3 * x3;
#pragma unroll
  for (int m = 1; m < 64; m <<= 1) ss += __shfl_xor(ss, m, 64);
  float inv = rsqrtf(ss * (1.0f / 256.0f) + 1e-6f);
  x0 *= inv * (1.0f + w[lane]);
  x1 *= inv * (1.0f + w[lane + 64]);
  x2 *= inv * (1.0f + w[lane + 128]);
  x3 *= inv * (1.0f + w[lane + 192]);
  float c0 = fc[lane], s0 = fs[lane], c1 = fc[lane + 64], s1 = fs[lane + 64];
  dst[lane]       = (f16)((x0 * c0 - x2 * s0) * scale);
  dst[lane + 64]  = (f16)((x1 * c1 - x3 * s1) * scale);
  dst[lane + 128] = (f16)((x0 * s0 + x2 * c0) * scale);
  dst[lane + 192] = (f16)((x1 * s1 + x3 * c1) * scale);
}

__global__ __launch_bounds__(256) void qkv_post(
    const f16* __restrict__ qkv, const float* __restrict__ qnw,
    const float* __restrict__ knw, const float* __restrict__ fcos,
    const float* __restrict__ fsin, f16* __restrict__ Q, f16* __restrict__ Kb) {
  long row = blockIdx.x;
  int b = (int)(row >> 11), s = (int)(row & 2047);
  int wave = threadIdx.x >> 6, lane = threadIdx.x & 63;
  const f16* base = qkv + row * QKV_N;
  const float* fc = fcos + (long)s * 128;
  const float* fs = fsin + (long)s * 128;
  norm_rope_store(base + wave * HD, qnw, fc, fs,
                  Q + ((long)(b * NH + wave) * SS + s) * HD, 0.0625f, lane);
  if (wave == 0)
    norm_rope_store(base + NH * HD, knw, fc, fs, Kb + row * HD, 1.0f, lane);
}

// ---------------------------------------------------------------------------
// Flash attention (R3 structure, proven 121 us), O written as fp16.
// grid: (48, NH, B), block 256 (4 waves x 16 q-rows), KVBLK=32.
// ---------------------------------------------------------------------------
__global__ __launch_bounds__(256, 3) void attn_fwd(
    const f16* __restrict__ Q, const f16* __restrict__ Kb,
    const f16* __restrict__ Vt, f16* __restrict__ O,
    f16* __restrict__ Opart, float2* __restrict__ ml) {
  __shared__ f16 Klds[32][264];
  __shared__ f16 Vlds[256][40];
  __shared__ f16 Plds[4][16][40];
  int it = blockIdx.x, h = blockIdx.y, b = blockIdx.z;
  int qb, t0, t1, pidx = 0;
  bool split;
  if (it < 16) {
    qb = it; t0 = 0; t1 = 2 * qb + 2; split = false;
  } else {
    int j = it - 16;
    qb = 16 + (j >> 1);
    int s = j & 1, half = qb + 1;
    t0 = s * half; t1 = t0 + half; split = true;
    pidx = (((b * NH + h) << 4) + (qb - 16)) * 2 + s;
  }
  int tid = threadIdx.x, wave = tid >> 6, lane = tid & 63;
  int l16 = lane & 15, lhi = lane >> 4;
  int q0 = qb * 64 + wave * 16;

  const f16* Kg = Kb + (long)b * SS * HD;
  const f16* Vg = Vt + (long)b * HD * SS;

  f16x8 qf[8];
  const f16* Qbase = Q + ((long)(b * NH + h) * SS + q0 + l16) * HD + lhi * 8;
#pragma unroll
  for (int kb = 0; kb < 8; ++kb) qf[kb] = *(const f16x8*)(Qbase + kb * 32);

  f32x4 o[16] = {};
  float m_i = -1e30f, l_i = 0.f;

  int kr = tid >> 5, kc = (tid & 31) * 8;
  int rv = tid >> 2, vc = (tid & 3) * 8;

  for (int t = t0; t < t1; ++t) {
    int kv0 = t * 32;
    __syncthreads();
#pragma unroll
    for (int i = 0; i < 4; ++i)
      *(uint4*)&Klds[kr + i * 8][kc] =
          *(const uint4*)(Kg + (long)(kv0 + kr + i * 8) * HD + kc);
#pragma unroll
    for (int i = 0; i < 4; ++i)
      *(uint4*)&Vlds[rv + i * 64][vc] =
          *(const uint4*)(Vg + (long)(rv + i * 64) * SS + kv0 + vc);
    __syncthreads();

    f32x4 sc[2] = {};
#pragma unroll
    for (int kb = 0; kb < 8; ++kb) {
#pragma unroll
      for (int cf = 0; cf < 2; ++cf) {
        f16x8 kf = *(const f16x8*)&Klds[cf * 16 + l16][kb * 32 + lhi * 8];
        sc[cf] = __builtin_amdgcn_mfma_f32_16x16x32_f16(kf, qf[kb], sc[cf], 0, 0, 0);
      }
    }

    float p[8];
    float mx = -1e30f;
    int qrow = q0 + l16;
    if (t >= 2 * qb) {
#pragma unroll
      for (int cf = 0; cf < 2; ++cf)
#pragma unroll
        for (int r = 0; r < 4; ++r) {
          int kv = kv0 + cf * 16 + lhi * 4 + r;
          float s = (kv <= qrow) ? sc[cf][r] : -1e30f;
          p[cf * 4 + r] = s;
          mx = fmaxf(mx, s);
        }
    } else {
#pragma unroll
      for (int i = 0; i < 8; ++i) {
        float s = sc[i >> 2][i & 3];
        p[i] = s;
        mx = fmaxf(mx, s);
      }
    }
    mx = fmaxf(mx, __shfl_xor(mx, 16));
    mx = fmaxf(mx, __shfl_xor(mx, 32));
    float mn = fmaxf(m_i, mx);
    float scl = __expf(m_i - mn);
    float rs = 0.f;
#pragma unroll
    for (int i = 0; i < 8; ++i) {
      p[i] = __expf(p[i] - mn);
      rs += p[i];
    }
    rs += __shfl_xor(rs, 16);
    rs += __shfl_xor(rs, 32);
    l_i = l_i * scl + rs;
    m_i = mn;

#pragma unroll
    for (int cf = 0; cf < 2; ++cf) {
      f16x4 hp = {(f16)p[cf * 4], (f16)p[cf * 4 + 1], (f16)p[cf * 4 + 2],
                  (f16)p[cf * 4 + 3]};
      *(f16x4*)&Plds[wave][l16][cf * 16 + lhi * 4] = hp;
    }

    float s0 = __shfl(scl, lhi * 4 + 0);
    float s1 = __shfl(scl, lhi * 4 + 1);
    float s2 = __shfl(scl, lhi * 4 + 2);
    float s3 = __shfl(scl, lhi * 4 + 3);
#pragma unroll
    for (int nf = 0; nf < 16; ++nf) {
      o[nf][0] *= s0;
      o[nf][1] *= s1;
      o[nf][2] *= s2;
      o[nf][3] *= s3;
    }

    f16x8 pa = *(const f16x8*)&Plds[wave][l16][lhi * 8];
#pragma unroll
    for (int nf = 0; nf < 16; ++nf) {
      f16x8 vf = *(const f16x8*)&Vlds[nf * 16 + l16][lhi * 8];
      o[nf] = __builtin_amdgcn_mfma_f32_16x16x32_f16(pa, vf, o[nf], 0, 0, 0);
    }
  }

  float inv = 1.0f / l_i;
  float i0 = __shfl(inv, lhi * 4 + 0);
  float i1 = __shfl(inv, lhi * 4 + 1);
  float i2 = __shfl(inv, lhi * 4 + 2);
  float i3 = __shfl(inv, lhi * 4 + 3);
  float ir[4] = {i0, i1, i2, i3};
  if (!split) {
#pragma unroll
    for (int r = 0; r < 4; ++r) {
      long srow = q0 + lhi * 4 + r;
      f16* Orow = O + ((long)b * SS + srow) * ODIM + h * HD + l16;
#pragma unroll
      for (int nf = 0; nf < 16; ++nf) Orow[nf * 16] = (f16)(o[nf][r] * ir[r]);
    }
  } else {
#pragma unroll
    for (int r = 0; r < 4; ++r) {
      int rloc = wave * 16 + lhi * 4 + r;
      f16* Prow = Opart + ((long)pidx * 64 + rloc) * HD + l16;
#pragma unroll
      for (int nf = 0; nf < 16; ++nf) Prow[nf * 16] = (f16)(o[nf][r] * ir[r]);
    }
    if (lane < 16) {
      float2 v; v.x = m_i; v.y = l_i;
      ml[(long)pidx * 64 + wave * 16 + lane] = v;
    }
  }
}

// ---------------------------------------------------------------------------
// Combine the two kv-split halves for qb >= 16 (fp16 out).
// ---------------------------------------------------------------------------
__global__ __launch_bounds__(256) void attn_combine(
    const f16* __restrict__ Opart, const float2* __restrict__ ml,
    f16* __restrict__ O) {
  int qx = blockIdx.x, h = blockIdx.y, b = blockIdx.z;
  int qb = 16 + qx;
  int p0 = (((b * NH + h) << 4) + qx) * 2;
  int tid = threadIdx.x;
  int r = tid >> 2, d0 = (tid & 3) * 64;
  float2 a = ml[(long)p0 * 64 + r];
  float2 c = ml[(long)(p0 + 1) * 64 + r];
  float M = fmaxf(a.x, c.x);
  float w0 = a.y * __expf(a.x - M), w1 = c.y * __expf(c.x - M);
  float invL = 1.0f / (w0 + w1);
  w0 *= invL; w1 *= invL;
  const f16* o0 = Opart + ((long)p0 * 64 + r) * HD + d0;
  const f16* o1 = Opart + ((long)(p0 + 1) * 64 + r) * HD + d0;
  f16* Orow = O + ((long)b * SS + qb * 64 + r) * ODIM + h * HD + d0;
#pragma unroll
  for (int i = 0; i < 8; ++i) {
    f16x8 x = *(const f16x8*)(o0 + i * 8);
    f16x8 y = *(const f16x8*)(o1 + i * 8);
    f16x8 z;
#pragma unroll
    for (int j = 0; j < 8; ++j)
      z[j] = (f16)(w0 * (float)x[j] + w1 * (float)y[j]);
    *(f16x8*)(Orow + i * 8) = z;
  }
}

// ---------------------------------------------------------------------------
extern "C" void kernel_launch(void* const* d_in, const int* in_sizes, int n_in,
                              void* d_out, int out_size, void* d_ws, size_t ws_size,
                              hipStream_t stream) {
  const float* hidden = (const float*)d_in[0];
  const float* fcos = (const float*)d_in[2];
  const float* fsin = (const float*)d_in[3];
  const float* wqkv = (const float*)d_in[4];
  const float* qnw = (const float*)d_in[5];
  const float* knw = (const float*)d_in[6];
  const float* wo = (const float*)d_in[7];
  float* out = (float*)d_out;

  char* ws = (char*)d_ws;
  f16* qkv16 = (f16*)(ws + QKV16_OFF);   // 25.2 MB
  f16* hid16 = (f16*)(ws + HID16_OFF);   // 18.9 MB (dead after gemm1)
  f16* Obuf = (f16*)(ws + OBUF_OFF);     // 16.8 MB (qkv dead by then)
  f16* Opart = (f16*)(ws + OPART_OFF);   // 16.8 MB (overlaps hid16: disjoint in time)
  f16* Qb = (f16*)(ws + QB_OFF);
  f16* Kb = (f16*)(ws + KB_OFF);
  f16* Vt = (f16*)(ws + VT_OFF);
  f16* wqkvt = (f16*)(ws + WQKVT_OFF);
  f16* wot = (f16*)(ws + WOT_OFF);
  float2* ml = (float2*)(ws + ML_OFF);

  // hidden fp32 -> fp16
  cvt_f32_to_f16<<<2048, 256, 0, stream>>>(hidden, hid16, (long)BB * SS * HID);

  // weight transposes -> fp16 [N][K]
  transpose_cvt<float><<<dim3(QKV_N / 32, HID / 32, 1), 256, 0, stream>>>(
      wqkv, QKV_N, 0, wqkvt, HID, 0);
  transpose_cvt<float><<<dim3(HID / 32, ODIM / 32, 1), 256, 0, stream>>>(
      wo, HID, 0, wot, ODIM, 0);

  // QKV GEMM -> qkv fp16
  gemm_f16<f16><<<dim3(BB * SS / 128, QKV_N / 128), 256, 0, stream>>>(
      hid16, wqkvt, qkv16, HID, QKV_N);

  // RMSNorm + RoPE -> Q, K fp16
  qkv_post<<<dim3(BB * SS), 256, 0, stream>>>(qkv16, qnw, knw, fcos, fsin, Qb, Kb);

  // V slice transpose: qkv16[b][s][1280+d] -> Vt[b][d][s]
  transpose_cvt<f16><<<dim3(HD / 32, SS / 32, BB), 256, 0, stream>>>(
      qkv16 + 1280, QKV_N, (long)SS * QKV_N, Vt, SS, (long)HD * SS);

  // flash attention -> Obuf fp16
  attn_fwd<<<dim3(48, NH, BB), 256, 0, stream>>>(Qb, Kb, Vt, Obuf, Opart, ml);
  attn_combine<<<dim3(16, NH, BB), 256, 0, stream>>>(Opart, ml, Obuf);

  // output GEMM -> d_out fp32
  gemm_f16<float><<<dim3(BB * SS / 128, HID / 128), 256, 0, stream>>>(
      Obuf, wot, out, ODIM, HID);
}